// Round 6
// baseline (82.420 us; speedup 1.0000x reference)
//
#include <hip/hip_runtime.h>
#include <hip/hip_bf16.h>

typedef __attribute__((ext_vector_type(4))) float f32x4;
typedef __attribute__((ext_vector_type(8))) short bf16x8;
typedef __attribute__((ext_vector_type(4))) unsigned short u16x4;

// B=2, S=2048, D=1024, H=16, HD=64
#define SB 2048
#define DD 1024
#define NH 16
#define HD 64
#define BH 32   // B*H

#define A_SCALE 0.42466089f   // sqrt(0.125 * log2(e)); (aQ)(aQ)^T = 0.125*log2e * QQ^T

static __device__ __forceinline__ unsigned short f2bf(float f) {
    union { float f; unsigned int u; } v; v.f = f;
    unsigned int lsb = (v.u >> 16) & 1u;
    v.u += 0x7fffu + lsb;           // RNE (inputs finite)
    return (unsigned short)(v.u >> 16);
}

// swizzled read from an LDS tile with 128B rows: byte col ^= (row&7)<<4
static __device__ __forceinline__ bf16x8 ld_swz128(const unsigned short* base, int row, int colb) {
    return *reinterpret_cast<const bf16x8*>(
        reinterpret_cast<const char*>(base) + row * 128 + (colb ^ ((row & 7) << 4)));
}

// Stage ROUNDS*4KB from global into LDS via global_load_lds (16B/lane), 256 threads.
// Linear LDS dest + inverse-swizzled global source (both-sides rule).
template<int ROUNDS>
static __device__ __forceinline__ void stage_swz(
    const char* gbase, int rowstrideB, unsigned short* lds, int tid)
{
    const int wave = tid >> 6;
    char* lb = (char*)lds + wave * 1024;
    #pragma unroll
    for (int rd = 0; rd < ROUNDS; ++rd) {
        int c = rd * 256 + tid;        // 16B chunk index
        int r = c >> 3, j = c & 7;     // row, chunk-in-row
        const char* src = gbase + (size_t)r * rowstrideB + ((j ^ (r & 7)) * 16);
        __builtin_amdgcn_global_load_lds(
            (const __attribute__((address_space(1))) unsigned int*)src,
            (__attribute__((address_space(3))) unsigned int*)(lb + rd * 4096),
            16, 0, 0);
    }
}

// Stage one 8KB [64][128B] tile with 512 threads (1 load/thread), swizzled.
static __device__ __forceinline__ void stage8(
    const char* gbase, int rowstrideB, unsigned short* lds, int tid)
{
    int r = tid >> 3, j = tid & 7;
    int wv = tid >> 6;
    const char* src = gbase + (size_t)r * rowstrideB + ((j ^ (r & 7)) * 16);
    __builtin_amdgcn_global_load_lds(
        (const __attribute__((address_space(1))) unsigned int*)src,
        (__attribute__((address_space(3))) unsigned int*)((char*)lds + wv * 1024),
        16, 0, 0);
}

// ---------------- cvt: f32 -> bf16 for X, Wq, Wv ----------------
__global__ __launch_bounds__(256) void cvt_kernel(
    const float* __restrict__ X, const float* __restrict__ Wq,
    const float* __restrict__ Wv,
    unsigned short* __restrict__ Xb, unsigned short* __restrict__ Wb)
{
    int i = blockIdx.x * 256 + threadIdx.x;   // 8 elements per thread
    const float* src; unsigned short* dst; size_t off;
    if (i < 524288)      { src = X;  dst = Xb;            off = (size_t)i * 8; }
    else if (i < 655360) { src = Wq; dst = Wb;            off = (size_t)(i - 524288) * 8; }
    else                 { src = Wv; dst = Wb + 1048576;  off = (size_t)(i - 655360) * 8; }
    f32x4 a = *reinterpret_cast<const f32x4*>(src + off);
    f32x4 b = *reinterpret_cast<const f32x4*>(src + off + 4);
    u16x4 pa, pb;
    #pragma unroll
    for (int j = 0; j < 4; ++j) { pa[j] = f2bf(a[j]); pb[j] = f2bf(b[j]); }
    *reinterpret_cast<u16x4*>(dst + off)     = pa;
    *reinterpret_cast<u16x4*>(dst + off + 4) = pb;
}

// ---------------- proj2: C[4096,1024] = Xb @ Wb[z]^T, m97 structure ----------------
// z=0 -> qbf (pre-scaled by A_SCALE); z=1 -> vt transposed.
__global__ __launch_bounds__(256, 2) void proj2_kernel(
    const unsigned short* __restrict__ Xb,   // [4096][1024]
    const unsigned short* __restrict__ Wb,   // [2048][1024]
    unsigned short* __restrict__ qbf,        // [32][2048][64]
    unsigned short* __restrict__ vt)         // [32][64][2048]
{
    __shared__ unsigned short As[2][128 * 64];
    __shared__ unsigned short Bs[2][128 * 64];
    const int z  = blockIdx.z;
    const int m0 = blockIdx.y * 128;
    const int n0 = blockIdx.x * 128;
    const int tid = threadIdx.x;
    const int wave = tid >> 6, lane = tid & 63;
    const int wr = wave >> 1, wc = wave & 1;
    const int lrow = lane & 15, lg = lane >> 4;

    const char* Ag = (const char*)Xb + (size_t)m0 * 2048;
    const char* Bg = (const char*)Wb + (size_t)(z * 1024 + n0) * 2048;

    f32x4 acc[4][4] = {};

    stage_swz<4>(Ag, 2048, As[0], tid);
    stage_swz<4>(Bg, 2048, Bs[0], tid);
    __syncthreads();

    int cur = 0;
    for (int kt = 0; kt < 16; ++kt) {
        if (kt + 1 < 16) {
            stage_swz<4>(Ag + (kt + 1) * 128, 2048, As[cur ^ 1], tid);
            stage_swz<4>(Bg + (kt + 1) * 128, 2048, Bs[cur ^ 1], tid);
        }
        bf16x8 af[4][2], bv[4][2];
        #pragma unroll
        for (int mf = 0; mf < 4; ++mf)
            #pragma unroll
            for (int kk = 0; kk < 2; ++kk)
                af[mf][kk] = ld_swz128(As[cur], wr * 64 + mf * 16 + lrow, kk * 64 + lg * 16);
        #pragma unroll
        for (int nf = 0; nf < 4; ++nf)
            #pragma unroll
            for (int kk = 0; kk < 2; ++kk)
                bv[nf][kk] = ld_swz128(Bs[cur], wc * 64 + nf * 16 + lrow, kk * 64 + lg * 16);
        #pragma unroll
        for (int kk = 0; kk < 2; ++kk)
            #pragma unroll
            for (int mf = 0; mf < 4; ++mf)
                #pragma unroll
                for (int nf = 0; nf < 4; ++nf)
                    acc[mf][nf] = __builtin_amdgcn_mfma_f32_16x16x32_bf16(
                        af[mf][kk], bv[nf][kk], acc[mf][nf], 0, 0, 0);
        __syncthreads();   // drains vmcnt (next bufs staged) + protects cur
        cur ^= 1;
    }

    const float sc = (z == 0) ? A_SCALE : 1.0f;
    const int lcol = lane & 15, lr4 = (lane >> 4) * 4;
    #pragma unroll
    for (int mf = 0; mf < 4; ++mf) {
        #pragma unroll
        for (int nf = 0; nf < 4; ++nf) {
            #pragma unroll
            for (int r = 0; r < 4; ++r) {
                int gm = m0 + wr * 64 + mf * 16 + lr4 + r;
                int gn = n0 + wc * 64 + nf * 16 + lcol;
                int b = gm >> 11, s = gm & (SB - 1);
                int h = gn >> 6,  e = gn & (HD - 1);
                unsigned short bvx = f2bf(acc[mf][nf][r] * sc);
                size_t bh = (size_t)(b * NH + h);
                if (z == 0) qbf[(bh * SB + s) * HD + e] = bvx;
                else        vt [(bh * HD + e) * SB + s] = bvx;
            }
        }
    }
}

// ---------------- attn: linear softmax, 8 waves / 128 q-rows share staged K/V ----------------
// grid (x=bh 32, y: qb128=15-y); 512 thr = 8 waves, wave owns 16 q-rows; KV tile 64.
// Q pre-scaled so S_exp2 = qf . kf directly; p = exp2(S), linear (no-max) softmax.
__global__ __launch_bounds__(512, 6) void attn_kernel(
    const unsigned short* __restrict__ qbf,  // [32][2048][64]
    const unsigned short* __restrict__ vt,   // [32][64][2048]
    float* __restrict__ out)                 // [2][2048][1024]
{
    __shared__ unsigned short Kl[2][64 * 64];    // 8KB per buf, swizzled
    __shared__ unsigned short Vl[2][64 * 64];
    __shared__ unsigned short p_lds[8][16][72];

    const int bh = blockIdx.x;
    const int qb = 15 - (int)blockIdx.y;       // LPT: longest first
    const int tid  = threadIdx.x;
    const int wave = tid >> 6, lane = tid & 63;
    const int lrow = lane & 15, lg = lane >> 4;
    const int wq0 = qb * 128 + wave * 16;      // this wave's first q-row
    const int T   = 2 * qb + 2;                // KV tiles for the block
    const char* Qg = (const char*)(qbf + (size_t)bh * (SB * HD));
    const char* Vg = (const char*)(vt  + (size_t)bh * (HD * SB));
    const unsigned short* Qh = qbf + (size_t)bh * (SB * HD);

    // Q A-frags
    bf16x8 qf[2];
    #pragma unroll
    for (int ks = 0; ks < 2; ++ks)
        qf[ks] = *reinterpret_cast<const bf16x8*>(Qh + (wq0 + lrow) * HD + ks * 32 + lg * 8);

    // prologue: stage tile 0
    stage8(Qg, 128, Kl[0], tid);
    stage8(Vg, 4096, Vl[0], tid);
    __syncthreads();

    f32x4 o_acc[4] = {};
    float l_lane[4] = {0.f, 0.f, 0.f, 0.f};
    int cur = 0;

    for (int t = 0; t < T; ++t) {
        const int kv0 = t * 64;
        if (t + 1 < T) {
            stage8(Qg + (size_t)(t + 1) * 8192, 128, Kl[cur ^ 1], tid);
            stage8(Vg + (size_t)(t + 1) * 128, 4096, Vl[cur ^ 1], tid);
        }

        if (kv0 <= wq0 + 15) {                 // tile not fully above my rows
            // QK^T from staged K
            f32x4 sacc[4];
            __builtin_amdgcn_s_setprio(1);
            #pragma unroll
            for (int nf = 0; nf < 4; ++nf) {
                f32x4 s = {0.f, 0.f, 0.f, 0.f};
                #pragma unroll
                for (int ks = 0; ks < 2; ++ks) {
                    bf16x8 bfr = ld_swz128(Kl[cur], nf * 16 + lrow, ks * 64 + lg * 16);
                    s = __builtin_amdgcn_mfma_f32_16x16x32_bf16(qf[ks], bfr, s, 0, 0, 0);
                }
                sacc[nf] = s;
            }
            __builtin_amdgcn_s_setprio(0);

            // p = exp2(s); per-lane l accumulation (linear softmax, f32-safe)
            if (kv0 + 63 > wq0) {              // diagonal-crossing: mask col > row
                #pragma unroll
                for (int nf = 0; nf < 4; ++nf) {
                    int col = kv0 + nf * 16 + lrow;
                    #pragma unroll
                    for (int r = 0; r < 4; ++r) {
                        int row = wq0 + lg * 4 + r;
                        float e = (col > row) ? 0.f : __builtin_amdgcn_exp2f(sacc[nf][r]);
                        l_lane[r] += e;
                        sacc[nf][r] = e;
                    }
                }
            } else {
                #pragma unroll
                for (int nf = 0; nf < 4; ++nf)
                    #pragma unroll
                    for (int r = 0; r < 4; ++r) {
                        float e = __builtin_amdgcn_exp2f(sacc[nf][r]);
                        l_lane[r] += e;
                        sacc[nf][r] = e;
                    }
            }

            // P -> p_lds (bf16) re-layout into A-frags (within-wave)
            #pragma unroll
            for (int nf = 0; nf < 4; ++nf)
                #pragma unroll
                for (int r = 0; r < 4; ++r)
                    p_lds[wave][lg * 4 + r][nf * 16 + lrow] = f2bf(sacc[nf][r]);

            // PV from staged V
            __builtin_amdgcn_s_setprio(1);
            #pragma unroll
            for (int ks = 0; ks < 2; ++ks) {
                bf16x8 pfr = *reinterpret_cast<const bf16x8*>(&p_lds[wave][lrow][ks * 32 + lg * 8]);
                #pragma unroll
                for (int ef = 0; ef < 4; ++ef) {
                    bf16x8 vf = ld_swz128(Vl[cur], ef * 16 + lrow, ks * 64 + lg * 16);
                    o_acc[ef] = __builtin_amdgcn_mfma_f32_16x16x32_bf16(pfr, vf, o_acc[ef], 0, 0, 0);
                }
            }
            __builtin_amdgcn_s_setprio(0);
        }

        __syncthreads();   // next-tile staging complete + buffers safe to overwrite
        cur ^= 1;
    }

    // l: reduce across 16 col-lanes; normalize and write final output
    #pragma unroll
    for (int msk = 1; msk <= 8; msk <<= 1)
        #pragma unroll
        for (int r = 0; r < 4; ++r)
            l_lane[r] += __shfl_xor(l_lane[r], msk);

    const int b = bh >> 4, h = bh & 15;
    #pragma unroll
    for (int r = 0; r < 4; ++r) {
        float inv = 1.f / l_lane[r];
        int row = wq0 + lg * 4 + r;
        float* orow = out + ((size_t)b * SB + row) * DD + h * HD;
        #pragma unroll
        for (int ef = 0; ef < 4; ++ef)
            orow[ef * 16 + lrow] = o_acc[ef][r] * inv;
    }
}

extern "C" void kernel_launch(void* const* d_in, const int* in_sizes, int n_in,
                              void* d_out, int out_size, void* d_ws, size_t ws_size,
                              hipStream_t stream) {
    const float* X  = (const float*)d_in[0];
    const float* Wq = (const float*)d_in[1];
    // d_in[2] = Wk: computed-but-unused in the reference output -> skipped
    const float* Wv = (const float*)d_in[3];
    float* out = (float*)d_out;

    unsigned short* qbf = (unsigned short*)d_ws;                   // 8 MB
    unsigned short* vtp = qbf + (size_t)BH * SB * HD;              // 8 MB
    unsigned short* Xb  = vtp + (size_t)BH * HD * SB;              // 8 MB
    unsigned short* Wb  = Xb  + (size_t)2 * SB * DD;               // 4 MB

    cvt_kernel<<<dim3(3072), dim3(256), 0, stream>>>(X, Wq, Wv, Xb, Wb);
    proj2_kernel<<<dim3(8, 32, 2), dim3(256), 0, stream>>>(Xb, Wb, qbf, vtp);
    attn_kernel<<<dim3(32, 16), dim3(512), 0, stream>>>(qbf, vtp, out);
}

// Round 7
// 79.669 us; speedup vs baseline: 1.0345x; 1.0345x over previous
//
#include <hip/hip_runtime.h>
#include <hip/hip_bf16.h>

typedef __attribute__((ext_vector_type(4))) float f32x4;
typedef __attribute__((ext_vector_type(8))) short bf16x8;
typedef __attribute__((ext_vector_type(4))) unsigned short u16x4;

// B=2, S=2048, D=1024, H=16, HD=64
#define SB 2048
#define DD 1024
#define NH 16
#define HD 64
#define BH 32   // B*H

#define A_SCALE 0.42466089f   // sqrt(0.125 * log2(e)); (aQ)(aQ)^T = 0.125*log2e * QQ^T

static __device__ __forceinline__ unsigned short f2bf(float f) {
    union { float f; unsigned int u; } v; v.f = f;
    unsigned int lsb = (v.u >> 16) & 1u;
    v.u += 0x7fffu + lsb;           // RNE (inputs finite)
    return (unsigned short)(v.u >> 16);
}

static __device__ __forceinline__ unsigned short f2bf_fast(float f) {
    __hip_bfloat16 h = __float2bfloat16(f);   // compiler emits v_cvt_pk_bf16_f32
    return *reinterpret_cast<unsigned short*>(&h);
}

// swizzled read from an LDS tile with 128B rows: byte col ^= (row&7)<<4
static __device__ __forceinline__ bf16x8 ld_swz128(const unsigned short* base, int row, int colb) {
    return *reinterpret_cast<const bf16x8*>(
        reinterpret_cast<const char*>(base) + row * 128 + (colb ^ ((row & 7) << 4)));
}

// Stage ROUNDS*4KB from global into LDS via global_load_lds (16B/lane), 256 threads.
template<int ROUNDS>
static __device__ __forceinline__ void stage_swz(
    const char* gbase, int rowstrideB, unsigned short* lds, int tid)
{
    const int wave = tid >> 6;
    char* lb = (char*)lds + wave * 1024;
    #pragma unroll
    for (int rd = 0; rd < ROUNDS; ++rd) {
        int c = rd * 256 + tid;        // 16B chunk index
        int r = c >> 3, j = c & 7;     // row, chunk-in-row
        const char* src = gbase + (size_t)r * rowstrideB + ((j ^ (r & 7)) * 16);
        __builtin_amdgcn_global_load_lds(
            (const __attribute__((address_space(1))) unsigned int*)src,
            (__attribute__((address_space(3))) unsigned int*)(lb + rd * 4096),
            16, 0, 0);
    }
}

// Stage one 8KB [64][128B] tile with 512 threads (1 load/thread), swizzled.
static __device__ __forceinline__ void stage8(
    const char* gbase, int rowstrideB, unsigned short* lds, int tid)
{
    int r = tid >> 3, j = tid & 7;
    int wv = tid >> 6;
    const char* src = gbase + (size_t)r * rowstrideB + ((j ^ (r & 7)) * 16);
    __builtin_amdgcn_global_load_lds(
        (const __attribute__((address_space(1))) unsigned int*)src,
        (__attribute__((address_space(3))) unsigned int*)((char*)lds + wv * 1024),
        16, 0, 0);
}

// ---------------- cvt: f32 -> bf16 for X, Wq, Wv ----------------
__global__ __launch_bounds__(256) void cvt_kernel(
    const float* __restrict__ X, const float* __restrict__ Wq,
    const float* __restrict__ Wv,
    unsigned short* __restrict__ Xb, unsigned short* __restrict__ Wb)
{
    int i = blockIdx.x * 256 + threadIdx.x;   // 8 elements per thread
    const float* src; unsigned short* dst; size_t off;
    if (i < 524288)      { src = X;  dst = Xb;            off = (size_t)i * 8; }
    else if (i < 655360) { src = Wq; dst = Wb;            off = (size_t)(i - 524288) * 8; }
    else                 { src = Wv; dst = Wb + 1048576;  off = (size_t)(i - 655360) * 8; }
    f32x4 a = *reinterpret_cast<const f32x4*>(src + off);
    f32x4 b = *reinterpret_cast<const f32x4*>(src + off + 4);
    u16x4 pa, pb;
    #pragma unroll
    for (int j = 0; j < 4; ++j) { pa[j] = f2bf(a[j]); pb[j] = f2bf(b[j]); }
    *reinterpret_cast<u16x4*>(dst + off)     = pa;
    *reinterpret_cast<u16x4*>(dst + off + 4) = pb;
}

// ---------------- proj2: C[4096,1024] = Xb @ Wb[z]^T, m97 structure ----------------
// z=0 -> qbf (pre-scaled by A_SCALE); z=1 -> vt transposed.
__global__ __launch_bounds__(256, 2) void proj2_kernel(
    const unsigned short* __restrict__ Xb,   // [4096][1024]
    const unsigned short* __restrict__ Wb,   // [2048][1024]
    unsigned short* __restrict__ qbf,        // [32][2048][64]
    unsigned short* __restrict__ vt)         // [32][64][2048]
{
    __shared__ unsigned short As[2][128 * 64];
    __shared__ unsigned short Bs[2][128 * 64];
    const int z  = blockIdx.z;
    const int m0 = blockIdx.y * 128;
    const int n0 = blockIdx.x * 128;
    const int tid = threadIdx.x;
    const int wave = tid >> 6, lane = tid & 63;
    const int wr = wave >> 1, wc = wave & 1;
    const int lrow = lane & 15, lg = lane >> 4;

    const char* Ag = (const char*)Xb + (size_t)m0 * 2048;
    const char* Bg = (const char*)Wb + (size_t)(z * 1024 + n0) * 2048;

    f32x4 acc[4][4] = {};

    stage_swz<4>(Ag, 2048, As[0], tid);
    stage_swz<4>(Bg, 2048, Bs[0], tid);
    __syncthreads();

    int cur = 0;
    for (int kt = 0; kt < 16; ++kt) {
        if (kt + 1 < 16) {
            stage_swz<4>(Ag + (kt + 1) * 128, 2048, As[cur ^ 1], tid);
            stage_swz<4>(Bg + (kt + 1) * 128, 2048, Bs[cur ^ 1], tid);
        }
        bf16x8 af[4][2], bv[4][2];
        #pragma unroll
        for (int mf = 0; mf < 4; ++mf)
            #pragma unroll
            for (int kk = 0; kk < 2; ++kk)
                af[mf][kk] = ld_swz128(As[cur], wr * 64 + mf * 16 + lrow, kk * 64 + lg * 16);
        #pragma unroll
        for (int nf = 0; nf < 4; ++nf)
            #pragma unroll
            for (int kk = 0; kk < 2; ++kk)
                bv[nf][kk] = ld_swz128(Bs[cur], wc * 64 + nf * 16 + lrow, kk * 64 + lg * 16);
        #pragma unroll
        for (int kk = 0; kk < 2; ++kk)
            #pragma unroll
            for (int mf = 0; mf < 4; ++mf)
                #pragma unroll
                for (int nf = 0; nf < 4; ++nf)
                    acc[mf][nf] = __builtin_amdgcn_mfma_f32_16x16x32_bf16(
                        af[mf][kk], bv[nf][kk], acc[mf][nf], 0, 0, 0);
        __syncthreads();
        cur ^= 1;
    }

    const float sc = (z == 0) ? A_SCALE : 1.0f;
    const int lcol = lane & 15, lr4 = (lane >> 4) * 4;
    #pragma unroll
    for (int mf = 0; mf < 4; ++mf) {
        #pragma unroll
        for (int nf = 0; nf < 4; ++nf) {
            #pragma unroll
            for (int r = 0; r < 4; ++r) {
                int gm = m0 + wr * 64 + mf * 16 + lr4 + r;
                int gn = n0 + wc * 64 + nf * 16 + lcol;
                int b = gm >> 11, s = gm & (SB - 1);
                int h = gn >> 6,  e = gn & (HD - 1);
                unsigned short bvx = f2bf(acc[mf][nf][r] * sc);
                size_t bh = (size_t)(b * NH + h);
                if (z == 0) qbf[(bh * SB + s) * HD + e] = bvx;
                else        vt [(bh * HD + e) * SB + s] = bvx;
            }
        }
    }
}

// ---------------- attn: linear softmax, depth-3 pipeline, counted vmcnt ----------------
// grid (x=bh 32, y=0..15); qb = y<8 ? 15-y : y-8  -> co-resident pairs (y,y+8) sum to
// uniform 34 tiles/CU. 512 thr = 8 waves, wave owns 16 q-rows; KV tile 64.
// Per tile: s_waitcnt vmcnt(counted) ; s_barrier ; compute ; s_barrier ; stage t+3.
__global__ __launch_bounds__(512, 4) void attn_kernel(
    const unsigned short* __restrict__ qbf,  // [32][2048][64]  (Q pre-scaled)
    const unsigned short* __restrict__ vt,   // [32][64][2048]
    float* __restrict__ out)                 // [2][2048][1024]
{
    __shared__ unsigned short Kl[3][64 * 64];    // 8KB per buf, swizzled
    __shared__ unsigned short Vl[3][64 * 64];
    __shared__ unsigned short p_lds[8][16][72];

    const int bh = blockIdx.x;
    const int y  = blockIdx.y;
    const int qb = (y < 8) ? (15 - y) : (y - 8);   // balance map
    const int tid  = threadIdx.x;
    const int wave = tid >> 6, lane = tid & 63;
    const int lrow = lane & 15, lg = lane >> 4;
    const int wq0 = qb * 128 + wave * 16;      // this wave's first q-row
    const int T   = 2 * qb + 2;                // KV tiles for the block
    const char* Qg = (const char*)(qbf + (size_t)bh * (SB * HD));
    const char* Vg = (const char*)(vt  + (size_t)bh * (HD * SB));
    const unsigned short* Qh = qbf + (size_t)bh * (SB * HD);

    // Q A-frags
    bf16x8 qf[2];
    #pragma unroll
    for (int ks = 0; ks < 2; ++ks)
        qf[ks] = *reinterpret_cast<const bf16x8*>(Qh + (wq0 + lrow) * HD + ks * 32 + lg * 8);

    // prologue: stage tiles 0..2 (each wave: 2 VMEM per tile)
    #pragma unroll
    for (int p = 0; p < 3; ++p) {
        if (p < T) {
            stage8(Qg + (size_t)p * 8192, 128, Kl[p], tid);
            stage8(Vg + (size_t)p * 128, 4096, Vl[p], tid);
        }
    }

    f32x4 o_acc[4] = {};
    float l_lane[4] = {0.f, 0.f, 0.f, 0.f};
    int cur = 0;

    for (int t = 0; t < T; ++t) {
        const int kv0 = t * 64;
        // gate: own loads for tile t retired (oldest); t+1,t+2 may stay in flight
        const int rem = T - 1 - t;
        if (rem >= 2)      asm volatile("s_waitcnt vmcnt(4)" ::: "memory");
        else if (rem == 1) asm volatile("s_waitcnt vmcnt(2)" ::: "memory");
        else               asm volatile("s_waitcnt vmcnt(0)" ::: "memory");
        __builtin_amdgcn_s_barrier();          // all waves' tile-t loads landed

        if (kv0 <= wq0 + 15) {                 // tile not fully above my rows
            // QK^T from staged K
            f32x4 sacc[4];
            __builtin_amdgcn_s_setprio(1);
            #pragma unroll
            for (int nf = 0; nf < 4; ++nf) {
                f32x4 s = {0.f, 0.f, 0.f, 0.f};
                #pragma unroll
                for (int ks = 0; ks < 2; ++ks) {
                    bf16x8 bfr = ld_swz128(Kl[cur], nf * 16 + lrow, ks * 64 + lg * 16);
                    s = __builtin_amdgcn_mfma_f32_16x16x32_bf16(qf[ks], bfr, s, 0, 0, 0);
                }
                sacc[nf] = s;
            }
            __builtin_amdgcn_s_setprio(0);

            // p = exp2(s); per-lane l accumulation (linear softmax, f32-safe)
            if (kv0 + 63 > wq0) {              // diagonal-crossing: mask col > row
                #pragma unroll
                for (int nf = 0; nf < 4; ++nf) {
                    int col = kv0 + nf * 16 + lrow;
                    #pragma unroll
                    for (int r = 0; r < 4; ++r) {
                        int row = wq0 + lg * 4 + r;
                        float e = (col > row) ? 0.f : __builtin_amdgcn_exp2f(sacc[nf][r]);
                        l_lane[r] += e;
                        sacc[nf][r] = e;
                    }
                }
            } else {
                #pragma unroll
                for (int nf = 0; nf < 4; ++nf)
                    #pragma unroll
                    for (int r = 0; r < 4; ++r) {
                        float e = __builtin_amdgcn_exp2f(sacc[nf][r]);
                        l_lane[r] += e;
                        sacc[nf][r] = e;
                    }
            }

            // P -> p_lds (bf16) re-layout into A-frags (within-wave)
            #pragma unroll
            for (int nf = 0; nf < 4; ++nf)
                #pragma unroll
                for (int r = 0; r < 4; ++r)
                    p_lds[wave][lg * 4 + r][nf * 16 + lrow] = f2bf_fast(sacc[nf][r]);

            // PV from staged V
            __builtin_amdgcn_s_setprio(1);
            #pragma unroll
            for (int ks = 0; ks < 2; ++ks) {
                bf16x8 pfr = *reinterpret_cast<const bf16x8*>(&p_lds[wave][lrow][ks * 32 + lg * 8]);
                #pragma unroll
                for (int ef = 0; ef < 4; ++ef) {
                    bf16x8 vf = ld_swz128(Vl[cur], ef * 16 + lrow, ks * 64 + lg * 16);
                    o_acc[ef] = __builtin_amdgcn_mfma_f32_16x16x32_bf16(pfr, vf, o_acc[ef], 0, 0, 0);
                }
            }
            __builtin_amdgcn_s_setprio(0);
        }

        __builtin_amdgcn_s_barrier();          // all waves done reading buf[cur]
        if (t + 3 < T) {                       // refill the just-read buffer
            stage8(Qg + (size_t)(t + 3) * 8192, 128, Kl[cur], tid);
            stage8(Vg + (size_t)(t + 3) * 128, 4096, Vl[cur], tid);
        }
        cur = (cur == 2) ? 0 : cur + 1;
    }

    // l: reduce across 16 col-lanes; normalize and write final output
    #pragma unroll
    for (int msk = 1; msk <= 8; msk <<= 1)
        #pragma unroll
        for (int r = 0; r < 4; ++r)
            l_lane[r] += __shfl_xor(l_lane[r], msk);

    const int b = bh >> 4, h = bh & 15;
    #pragma unroll
    for (int r = 0; r < 4; ++r) {
        float inv = 1.f / l_lane[r];
        int row = wq0 + lg * 4 + r;
        float* orow = out + ((size_t)b * SB + row) * DD + h * HD;
        #pragma unroll
        for (int ef = 0; ef < 4; ++ef)
            orow[ef * 16 + lrow] = o_acc[ef][r] * inv;
    }
}

extern "C" void kernel_launch(void* const* d_in, const int* in_sizes, int n_in,
                              void* d_out, int out_size, void* d_ws, size_t ws_size,
                              hipStream_t stream) {
    const float* X  = (const float*)d_in[0];
    const float* Wq = (const float*)d_in[1];
    // d_in[2] = Wk: computed-but-unused in the reference output -> skipped
    const float* Wv = (const float*)d_in[3];
    float* out = (float*)d_out;

    unsigned short* qbf = (unsigned short*)d_ws;                   // 8 MB
    unsigned short* vtp = qbf + (size_t)BH * SB * HD;              // 8 MB
    unsigned short* Xb  = vtp + (size_t)BH * HD * SB;              // 8 MB
    unsigned short* Wb  = Xb  + (size_t)2 * SB * DD;               // 4 MB

    cvt_kernel<<<dim3(3072), dim3(256), 0, stream>>>(X, Wq, Wv, Xb, Wb);
    proj2_kernel<<<dim3(8, 32, 2), dim3(256), 0, stream>>>(Xb, Wb, qbf, vtp);
    attn_kernel<<<dim3(32, 16), dim3(512), 0, stream>>>(qbf, vtp, out);
}